// Round 10
// baseline (3333.887 us; speedup 1.0000x reference)
//
#include <hip/hip_runtime.h>
#include <math.h>

// Problem constants
#define Bn 256
#define Tn 100
#define In 1024
#define Hn 2048
#define On 10
#define Kc (In + Hn)   // 3072 concatenated K

typedef short s8v  __attribute__((ext_vector_type(8)));   // 8 x bf16 (as raw shorts), 4 VGPRs
typedef unsigned short us2 __attribute__((ext_vector_type(2)));
typedef float f32x4 __attribute__((ext_vector_type(4)));

__device__ __forceinline__ unsigned short f2bf(float f) {
    unsigned int u = __float_as_uint(f);
    u += 0x7fffu + ((u >> 16) & 1u);   // round-to-nearest-even
    return (unsigned short)(u >> 16);
}

// tanh(x) = 1 - 2/(e^(2x)+1): v_exp_f32 + v_rcp_f32, ~2e-7 rel err (<< bf16 eps).
__device__ __forceinline__ float ftanh(float x) {
    float e = exp2f(x * 2.885390081777927f);          // e^(2x)
    return 1.f - 2.f * __builtin_amdgcn_rcpf(e + 1.f);
}

// ---- setup kernels -------------------------------------------------------

// x [B][T][I] fp32 -> bf16, 4 elems/thread
__global__ void conv_x_kernel(const float4* __restrict__ src, ushort4* __restrict__ dst) {
    int i = blockIdx.x * 256 + threadIdx.x;
    float4 v = src[i];
    ushort4 o;
    o.x = f2bf(v.x); o.y = f2bf(v.y); o.z = f2bf(v.z); o.w = f2bf(v.w);
    dst[i] = o;
}

// src [K][N=2048] fp32 -> dst[n][colOff + k] bf16  (builds B^T = [Win;W]^T rows)
__global__ void transpose_bf16_kernel(const float* __restrict__ src, unsigned short* __restrict__ dst,
                                      int N, int ld, int colOff) {
    __shared__ float tile[32][33];
    int k0 = blockIdx.x * 32;
    int n0 = blockIdx.y * 32;
    int c = threadIdx.x & 31;
    int r = threadIdx.x >> 5;            // 0..7
    #pragma unroll
    for (int i = 0; i < 32; i += 8)
        tile[r + i][c] = src[(size_t)(k0 + r + i) * N + n0 + c];
    __syncthreads();
    #pragma unroll
    for (int i = 0; i < 32; i += 8)
        dst[(size_t)(n0 + r + i) * ld + colOff + k0 + c] = f2bf(tile[c][r + i]);
}

// h0 -> h_all slot 0 (bf16); lin_w -> padded bf16 [16][2048]; zero barrier slots
__global__ void small_conv_kernel(const float* __restrict__ h0, const float* __restrict__ lin_w,
                                  unsigned short* __restrict__ h_all0, unsigned short* __restrict__ lwb,
                                  unsigned int* __restrict__ bar) {
    int idx = blockIdx.x * 256 + threadIdx.x;
    if (idx < 512) bar[idx] = 0u;        // 4 groups x 128 slots (re-zeroed every launch)
    if (idx < Bn * Hn) {
        h_all0[idx] = f2bf(h0[idx]);
    } else {
        int j = idx - Bn * Hn;           // < 16*2048 exactly (grid sized for it)
        int o = j >> 11;
        int k = j & 2047;
        lwb[j] = (o < On) ? f2bf(lin_w[o * Hn + k]) : (unsigned short)0;
    }
}

// ---- persistent scan -----------------------------------------------------
// R10: 512 blocks x 512 thr => 2 blocks/CU, 16 waves/CU (4/SIMD). Rationale:
// R5-R9 exonerated barrier mechanics, coherence path, and VGPR pipelining —
// all variants pinned at ~13.8us/step with Occupancy 24.7% (8 waves/CU,
// 1 block/CU). The stall is exposed memory latency + a serial barrier window
// during which the whole CU idles. Fix: (a) 2x waves for 2x outstanding
// loads; (b) co-resident blocks are in DIFFERENT m-groups (mgrp from bit8 &
// bit2 of blockIdx: g vs g+256 and g vs g+4 differ), and since the 4
// m-group barriers are independent (R9), one block's barrier wait overlaps
// the other block's MFMA work.
// Tile: 64m x 16n, K split 8 ways per block (384/wave). VGPR ~<=128 for
// 4 waves/EU; LDS 20KB/block (2 resident). Sync machinery = R9 (proven):
// write-through h stores, per-group slot-store + 64-lane ballot poll.
__global__ __launch_bounds__(512, 4)
void scan_kernel(const unsigned short* __restrict__ xb,
                 const unsigned short* __restrict__ BTm,
                 unsigned short* __restrict__ h_all,
                 unsigned int* __restrict__ bar) {
    const int g = blockIdx.x;
    const int mgrp = ((g >> 8) << 1) | ((g >> 2) & 1);  // co-resident pairs differ
    const int m0 = mgrp * 64;
    const int nid = ((g >> 3) & 31) * 4 + (g & 3);      // 0..127
    const int n0 = nid * 16;                            // 128 n-tiles of 16
    const int w = threadIdx.x >> 6;                     // 0..7
    const int lane = threadIdx.x & 63;
    const int quad = lane >> 4;
    const int lr = lane & 15;

    __shared__ float red[4][64][20];                    // 20KB; stride 20: 2-way banks (free)

    const unsigned short* bp0 = BTm + (size_t)(n0 + lr) * Kc;
    const size_t xrow = (size_t)Tn * In;                // x row stride (102400)

    unsigned int* myslot = bar + mgrp * 128 + nid;      // this block's arrival slot
    unsigned int* grpbase = bar + mgrp * 128;           // group's 128 slots (8 lines)

    // ---- one-time B-fragment preload (single n-tile per wave-chunk) ------
    s8v bx[4];                                          // x-region B frags
    s8v bh[8];                                          // h-region B frags
    #pragma unroll
    for (int c = 0; c < 4; ++c)
        bx[c] = *(const s8v*)(bp0 + w * 128 + c * 32 + quad * 8);
    #pragma unroll
    for (int c = 0; c < 8; ++c)
        bh[c] = *(const s8v*)(bp0 + In + w * 256 + c * 32 + quad * 8);

    f32x4 acc[4];
    #pragma unroll
    for (int mi = 0; mi < 4; ++mi)
        acc[mi] = (f32x4){0.f, 0.f, 0.f, 0.f};

    // ---- x-part for t=0 ----
    {
        const unsigned short* xt = xb;
        #pragma unroll
        for (int c = 0; c < 4; ++c) {
            const int kq = w * 128 + c * 32 + quad * 8;
            const unsigned short* arow = xt + kq + (size_t)(m0 + lr) * xrow;
            s8v a0 = *(const s8v*)(arow);
            s8v a1 = *(const s8v*)(arow + 16 * xrow);
            s8v a2 = *(const s8v*)(arow + 32 * xrow);
            s8v a3 = *(const s8v*)(arow + 48 * xrow);
            acc[0] = __builtin_amdgcn_mfma_f32_16x16x32_bf16(a0, bx[c], acc[0], 0, 0, 0);
            acc[1] = __builtin_amdgcn_mfma_f32_16x16x32_bf16(a1, bx[c], acc[1], 0, 0, 0);
            acc[2] = __builtin_amdgcn_mfma_f32_16x16x32_bf16(a2, bx[c], acc[2], 0, 0, 0);
            acc[3] = __builtin_amdgcn_mfma_f32_16x16x32_bf16(a3, bx[c], acc[3], 0, 0, 0);
        }
    }

    for (int t = 0; t < Tn; ++t) {
        // ---- h-part (gated on this m-group's barrier of step t-1) ----
        const unsigned short* hprev = h_all + (size_t)t * (Bn * Hn);
        #pragma unroll
        for (int c = 0; c < 8; ++c) {
            const int kq = w * 256 + c * 32 + quad * 8;            // offset inside h
            const unsigned short* arow = hprev + kq + (size_t)(m0 + lr) * Hn;
            s8v a0 = *(const s8v*)(arow);
            s8v a1 = *(const s8v*)(arow + 16 * Hn);
            s8v a2 = *(const s8v*)(arow + 32 * Hn);
            s8v a3 = *(const s8v*)(arow + 48 * Hn);
            acc[0] = __builtin_amdgcn_mfma_f32_16x16x32_bf16(a0, bh[c], acc[0], 0, 0, 0);
            acc[1] = __builtin_amdgcn_mfma_f32_16x16x32_bf16(a1, bh[c], acc[1], 0, 0, 0);
            acc[2] = __builtin_amdgcn_mfma_f32_16x16x32_bf16(a2, bh[c], acc[2], 0, 0, 0);
            acc[3] = __builtin_amdgcn_mfma_f32_16x16x32_bf16(a3, bh[c], acc[3], 0, 0, 0);
        }

        // ---- LDS reduce: C/D layout row=quad*4+reg, col=lane&15 [m89/m91] ----
        if (w < 4) {
            #pragma unroll
            for (int mi = 0; mi < 4; ++mi)
                #pragma unroll
                for (int rr = 0; rr < 4; ++rr)
                    red[w][mi * 16 + quad * 4 + rr][lr] = acc[mi][rr];
        }
        __syncthreads();
        if (w >= 4) {
            #pragma unroll
            for (int mi = 0; mi < 4; ++mi)
                #pragma unroll
                for (int rr = 0; rr < 4; ++rr)
                    red[w - 4][mi * 16 + quad * 4 + rr][lr] += acc[mi][rr];
        }
        __syncthreads();

        {   // 512 threads x 2 outputs: reduce 4 partials, tanh, 4B store
            int j = threadIdx.x << 1;
            int row = j >> 4;
            int c0 = j & 15;
            float2 s0 = *(const float2*)&red[0][row][c0];
            float2 s1 = *(const float2*)&red[1][row][c0];
            float2 s2 = *(const float2*)&red[2][row][c0];
            float2 s3 = *(const float2*)&red[3][row][c0];
            us2 o2;
            o2[0] = f2bf(ftanh(s0.x + s1.x + s2.x + s3.x));
            o2[1] = f2bf(ftanh(s0.y + s1.y + s2.y + s3.y));
            unsigned int* dst = (unsigned int*)
                (h_all + (size_t)(t + 1) * (Bn * Hn) + (size_t)(m0 + row) * Hn + n0 + c0);
            __hip_atomic_store(dst, __builtin_bit_cast(unsigned int, o2),
                               __ATOMIC_RELAXED, __HIP_MEMORY_SCOPE_AGENT);
        }

        if (t < Tn - 1) {
            // ---- cross-barrier fill: next step's x-part ----
            #pragma unroll
            for (int mi = 0; mi < 4; ++mi)
                acc[mi] = (f32x4){0.f, 0.f, 0.f, 0.f};
            const unsigned short* xt = xb + (size_t)(t + 1) * In;
            #pragma unroll
            for (int c = 0; c < 4; ++c) {
                const int kq = w * 128 + c * 32 + quad * 8;
                const unsigned short* arow = xt + kq + (size_t)(m0 + lr) * xrow;
                s8v a0 = *(const s8v*)(arow);
                s8v a1 = *(const s8v*)(arow + 16 * xrow);
                s8v a2 = *(const s8v*)(arow + 32 * xrow);
                s8v a3 = *(const s8v*)(arow + 48 * xrow);
                acc[0] = __builtin_amdgcn_mfma_f32_16x16x32_bf16(a0, bx[c], acc[0], 0, 0, 0);
                acc[1] = __builtin_amdgcn_mfma_f32_16x16x32_bf16(a1, bx[c], acc[1], 0, 0, 0);
                acc[2] = __builtin_amdgcn_mfma_f32_16x16x32_bf16(a2, bx[c], acc[2], 0, 0, 0);
                acc[3] = __builtin_amdgcn_mfma_f32_16x16x32_bf16(a3, bx[c], acc[3], 0, 0, 0);
            }

            __syncthreads();                             // all waves' h stores drained (vmcnt0)
            if (threadIdx.x == 0)                        // arrival: plain slot store, no RMW
                __hip_atomic_store(myslot, (unsigned int)(t + 1),
                                   __ATOMIC_RELAXED, __HIP_MEMORY_SCOPE_AGENT);
            if (w == 0) {                                // 64-lane ballot poll: 128 slots via 8B loads
                const unsigned int tp1 = (unsigned int)(t + 1);
                unsigned long long* s = (unsigned long long*)grpbase + lane;
                for (;;) {
                    unsigned long long v = __hip_atomic_load(s, __ATOMIC_RELAXED,
                                                             __HIP_MEMORY_SCOPE_AGENT);
                    unsigned int lo = (unsigned int)v;
                    unsigned int hi = (unsigned int)(v >> 32);
                    if (__ballot(lo < tp1 || hi < tp1) == 0ull) break;
                    __builtin_amdgcn_s_sleep(1);
                }
            }
            __syncthreads();
        }
    }
}

// ---- output projection ---------------------------------------------------
// y[b][t][o] = h_all[t+1][b][:] . lin_w[o][:] + lin_b[o]. One 16-row wave per 16 (t,b) rows.
__global__ __launch_bounds__(256)
void gemm2_kernel(const unsigned short* __restrict__ h_all, const unsigned short* __restrict__ lwb,
                  const float* __restrict__ lb, float* __restrict__ y) {
    int gw = blockIdx.x * 4 + (threadIdx.x >> 6);       // 0..1599
    int lane = threadIdx.x & 63, quad = lane >> 4, lr = lane & 15;
    int m0 = gw * 16;
    int t = m0 >> 8;
    int b0 = m0 & 255;
    const unsigned short* ah = h_all + ((size_t)(t + 1) * Bn + b0 + lr) * Hn + quad * 8;
    const unsigned short* bh = lwb + (size_t)lr * Hn + quad * 8;
    f32x4 acc0 = {0.f, 0.f, 0.f, 0.f}, acc1 = {0.f, 0.f, 0.f, 0.f};
    #pragma unroll
    for (int k0 = 0; k0 < Hn; k0 += 64) {
        s8v a0 = *(const s8v*)(ah + k0);
        s8v b0 = *(const s8v*)(bh + k0);
        acc0 = __builtin_amdgcn_mfma_f32_16x16x32_bf16(a0, b0, acc0, 0, 0, 0);
        s8v a1 = *(const s8v*)(ah + k0 + 32);
        s8v b1 = *(const s8v*)(bh + k0 + 32);
        acc1 = __builtin_amdgcn_mfma_f32_16x16x32_bf16(a1, b1, acc1, 0, 0, 0);
    }
    acc0 = acc0 + acc1;
    if (lr < On) {
        float bias = lb[lr];
        #pragma unroll
        for (int rr = 0; rr < 4; ++rr) {
            int b = b0 + quad * 4 + rr;
            y[(size_t)b * (Tn * On) + t * On + lr] = acc0[rr] + bias;
        }
    }
}

// ---- host ----------------------------------------------------------------

extern "C" void kernel_launch(void* const* d_in, const int* in_sizes, int n_in,
                              void* d_out, int out_size, void* d_ws, size_t ws_size,
                              hipStream_t stream) {
    const float* x   = (const float*)d_in[0];
    const float* h0  = (const float*)d_in[1];
    const float* Win = (const float*)d_in[2];
    const float* W   = (const float*)d_in[3];
    const float* lw  = (const float*)d_in[4];
    const float* lb  = (const float*)d_in[5];
    float* y = (float*)d_out;

    // ws layout (bf16 elems): ~171 MB total
    unsigned short* ws    = (unsigned short*)d_ws;
    unsigned short* xb    = ws;                                  // 26,214,400 elems
    unsigned short* BTm   = xb + (size_t)Bn * Tn * In;           //  6,291,456 elems [2048][3072]
    unsigned short* h_all = BTm + (size_t)Hn * Kc;               // 52,953,088 elems [(T+1)][B][H]
    unsigned short* lwb   = h_all + (size_t)(Tn + 1) * Bn * Hn;  //     32,768 elems [16][2048]
    unsigned int*   bar   = (unsigned int*)(lwb + 32768);        // 512 arrival slots

    conv_x_kernel<<<25600, 256, 0, stream>>>((const float4*)x, (ushort4*)xb);
    transpose_bf16_kernel<<<dim3(32, 64), 256, 0, stream>>>(Win, BTm, Hn, Kc, 0);
    transpose_bf16_kernel<<<dim3(64, 64), 256, 0, stream>>>(W, BTm, Hn, Kc, In);
    small_conv_kernel<<<2176, 256, 0, stream>>>(h0, lw, h_all, lwb, bar);

    scan_kernel<<<512, 512, 0, stream>>>(xb, BTm, h_all, bar);

    gemm2_kernel<<<400, 256, 0, stream>>>(h_all, lwb, lb, y);
}